// Round 4
// baseline (1143.901 us; speedup 1.0000x reference)
//
#include <hip/hip_runtime.h>
#include <hip/hip_bf16.h>
#include <stdint.h>

#define N_ROWS 2048
#define DK 1024
#define NU 50257
#define NS 8192

typedef __bf16 bf16x8 __attribute__((ext_vector_type(8)));
typedef float f32x4 __attribute__((ext_vector_type(4)));
typedef float vf4 __attribute__((ext_vector_type(4)));   // clang-native for nt builtins
typedef unsigned vu2 __attribute__((ext_vector_type(2)));
typedef unsigned vu4 __attribute__((ext_vector_type(4)));

__device__ __forceinline__ unsigned short f2bf_rne(float f) {
  union { float f; unsigned u; } v; v.f = f;
  unsigned u = v.u;
  return (unsigned short)((u + 0x7FFFu + ((u >> 16) & 1u)) >> 16);
}
__device__ __forceinline__ unsigned pack2(float lo, float hi) {
  return (unsigned)f2bf_rne(lo) | ((unsigned)f2bf_rne(hi) << 16);
}

// ---------- fp32 -> bf16 bulk convert (8 elems/thread, 16B stores) ----------
__global__ void cvt_f32_bf16(const float* __restrict__ in,
                             unsigned short* __restrict__ out, unsigned n) {
  unsigned i = (blockIdx.x * 256u + threadIdx.x) * 8u;
  if (i >= n) return;
  const vf4* p = (const vf4*)(in + i);
  vf4 a = __builtin_nontemporal_load(p);
  vf4 b = __builtin_nontemporal_load(p + 1);
  vu4 o;
  o.x = pack2(a.x, a.y); o.y = pack2(a.z, a.w);
  o.z = pack2(b.x, b.y); o.w = pack2(b.z, b.w);
  *(vu4*)(out + i) = o;
}

// ---------- per-sampled-col adjust term (bias - log(S) - logq) ----------
__global__ void compute_adj(const float* __restrict__ bias,
                            const int* __restrict__ sampled,
                            float* __restrict__ adj) {
  int j = blockIdx.x * 256 + threadIdx.x;
  if (j < NS) {
    int s = sampled[j];
    float lq = logf(log1pf(1.0f / ((float)s + 1.0f))) - logf(logf((float)(NU + 1)));
    adj[j] = bias[s] - (logf((float)NS) + lq);
  }
}

// ---------- true logit per row (fp32 dot), adds exp(tl) into loss accum ----------
__global__ void true_logits_k(const float* __restrict__ x, const float* __restrict__ kern,
                              const float* __restrict__ bias, const int* __restrict__ targets,
                              float* __restrict__ true_logit, float* __restrict__ loss_acc) {
  int row = blockIdx.x * 4 + (threadIdx.x >> 6);
  int lane = threadIdx.x & 63;
  int t = targets[row];
  const float* xr = x + (size_t)row * DK;
  const float* wr = kern + (size_t)t * DK;
  float s = 0.f;
  #pragma unroll
  for (int it = 0; it < 4; ++it) {
    int c = lane * 4 + it * 256;
    float4 a = *(const float4*)(xr + c);
    float4 b = *(const float4*)(wr + c);
    s += a.x * b.x + a.y * b.y + a.z * b.z + a.w * b.w;
  }
  #pragma unroll
  for (int off = 32; off > 0; off >>= 1) s += __shfl_xor(s, off, 64);
  if (lane == 0) {
    float lq = logf(log1pf(1.0f / ((float)t + 1.0f))) - logf(logf((float)(NU + 1)));
    float tl = s + bias[t] - (logf((float)NS) + lq);
    true_logit[row] = tl;
    atomicAdd(&loss_acc[row], __expf(tl));
  }
}

// ---------- main GEMM: probs numerator + row sums ----------
// XCD-chunk swizzle (6288 = 8*786, bijective), row-inner -> B panel L2-reused
// 16x. Epilogue: LDS-staged 32x128 tile -> alignment-aware nt stores (row base
// mod 4 varies since NU%4==1; misaligned 16B stores straddle sectors = 1.36x
// write amplification observed at R2).
__global__ __launch_bounds__(256) void gemm_probs(
    const unsigned short* __restrict__ A,   // x bf16 [2048,1024]
    const unsigned short* __restrict__ Bm,  // kernel bf16 [NU,1024]
    const float* __restrict__ bias,
    float* __restrict__ out, float* __restrict__ row_sum) {
  __shared__ alignas(16) unsigned char smem[32 * 132 * 4];
  unsigned short* As = (unsigned short*)smem;
  unsigned short* Bs = (unsigned short*)(smem + 8192);
  float* ot = (float*)smem;

  const int tid = threadIdx.x;
  const int wave = tid >> 6, lane = tid & 63;
  const int bid = blockIdx.x;
  const int sb = (bid & 7) * 786 + (bid >> 3);   // XCD-chunk swizzle
  const int rb = (sb & 15) << 7;                 // row tile (inner)
  const int cb = (sb >> 4) << 7;                 // col panel (outer)
  const int wm = wave & 1, wn = wave >> 1;
  const int q = lane >> 4, l15 = lane & 15;
  const int srow = lane >> 2, scol = lane & 3;

  f32x4 acc[4][4] = {};

  const int seg0 = wave * 2;
  const unsigned short* ga0 = A + (size_t)(rb + seg0 * 16 + srow) * DK + scol * 8;
  const unsigned short* ga1 = ga0 + (size_t)16 * DK;
  int bu0 = cb + seg0 * 16 + srow;       if (bu0 > NU - 1) bu0 = NU - 1;
  int bu1 = cb + (seg0 + 1) * 16 + srow; if (bu1 > NU - 1) bu1 = NU - 1;
  const unsigned short* gb0 = Bm + (size_t)bu0 * DK + scol * 8;
  const unsigned short* gb1 = Bm + (size_t)bu1 * DK + scol * 8;
  unsigned short* la0 = As + (seg0) * 512;
  unsigned short* la1 = As + (seg0 + 1) * 512;
  unsigned short* lb0 = Bs + (seg0) * 512;
  unsigned short* lb1 = Bs + (seg0 + 1) * 512;

  for (int kb = 0; kb < DK; kb += 32) {
    __builtin_amdgcn_global_load_lds((__attribute__((address_space(1))) void*)(ga0 + kb),
                                     (__attribute__((address_space(3))) void*)la0, 16, 0, 0);
    __builtin_amdgcn_global_load_lds((__attribute__((address_space(1))) void*)(ga1 + kb),
                                     (__attribute__((address_space(3))) void*)la1, 16, 0, 0);
    __builtin_amdgcn_global_load_lds((__attribute__((address_space(1))) void*)(gb0 + kb),
                                     (__attribute__((address_space(3))) void*)lb0, 16, 0, 0);
    __builtin_amdgcn_global_load_lds((__attribute__((address_space(1))) void*)(gb1 + kb),
                                     (__attribute__((address_space(3))) void*)lb1, 16, 0, 0);
    __syncthreads();
    bf16x8 af[4], bfr[4];
    #pragma unroll
    for (int mi = 0; mi < 4; ++mi)
      af[mi] = *(const bf16x8*)&As[(wm * 64 + mi * 16 + l15) * 32 + q * 8];
    #pragma unroll
    for (int ni = 0; ni < 4; ++ni)
      bfr[ni] = *(const bf16x8*)&Bs[(wn * 64 + ni * 16 + l15) * 32 + q * 8];
    #pragma unroll
    for (int mi = 0; mi < 4; ++mi)
      #pragma unroll
      for (int ni = 0; ni < 4; ++ni)
        acc[mi][ni] = __builtin_amdgcn_mfma_f32_16x16x32_bf16(af[mi], bfr[ni], acc[mi][ni], 0, 0, 0);
    __syncthreads();
  }

  // ---- epilogue: per mi-slice, stage 32x128 exp-tile in LDS, write coalesced
  const bool full_panel = (cb + 128 <= NU);
  #pragma unroll
  for (int mi = 0; mi < 4; ++mi) {
    // Phase A: fragment -> LDS with bias + exp
    #pragma unroll
    for (int ni = 0; ni < 4; ++ni) {
      int col = cb + wn * 64 + ni * 16 + l15;
      int bcol = col < NU ? col : NU - 1;   // clamp: avoid OOB bias read
      float bv = bias[bcol];
      f32x4 c = acc[mi][ni];
      #pragma unroll
      for (int r = 0; r < 4; ++r)
        ot[(wm * 16 + q * 4 + r) * 132 + wn * 64 + ni * 16 + l15] = __expf(c[r] + bv);
    }
    __syncthreads();
    // Phase B: coalesced, alignment-aware write-back + row sums.
    {
      int lr = tid >> 3;          // 0..31 local row
      int sub = tid & 7;          // 0..7
      int grow = rb + (lr >> 4) * 64 + mi * 16 + (lr & 15);
      size_t base = (size_t)grow * NU + cb;
      float* gout = out + base;
      const float* lrow = ot + lr * 132;
      float sum = 0.f;
      if (full_panel) {
        int c0 = sub * 16;
        vf4 v0 = *(const vf4*)(lrow + c0);
        vf4 v1 = *(const vf4*)(lrow + c0 + 4);
        vf4 v2 = *(const vf4*)(lrow + c0 + 8);
        vf4 v3 = *(const vf4*)(lrow + c0 + 12);
        sum = v0.x + v0.y + v0.z + v0.w + v1.x + v1.y + v1.z + v1.w
            + v2.x + v2.y + v2.z + v2.w + v3.x + v3.y + v3.z + v3.w;
        float* g = gout + c0;
        int mis = (int)((4 - (base & 3)) & 3);  // same for whole row; NU%4==1 -> mis=(4-(grow&3))&3
        vf4 t;
        switch (mis) {
          case 0:
            __builtin_nontemporal_store(v0, (vf4*)g);
            __builtin_nontemporal_store(v1, (vf4*)(g + 4));
            __builtin_nontemporal_store(v2, (vf4*)(g + 8));
            __builtin_nontemporal_store(v3, (vf4*)(g + 12));
            break;
          case 1:
            __builtin_nontemporal_store(v0.x, g);
            t.x = v0.y; t.y = v0.z; t.z = v0.w; t.w = v1.x;
            __builtin_nontemporal_store(t, (vf4*)(g + 1));
            t.x = v1.y; t.y = v1.z; t.z = v1.w; t.w = v2.x;
            __builtin_nontemporal_store(t, (vf4*)(g + 5));
            t.x = v2.y; t.y = v2.z; t.z = v2.w; t.w = v3.x;
            __builtin_nontemporal_store(t, (vf4*)(g + 9));
            __builtin_nontemporal_store(v3.y, g + 13);
            __builtin_nontemporal_store(v3.z, g + 14);
            __builtin_nontemporal_store(v3.w, g + 15);
            break;
          case 2:
            __builtin_nontemporal_store(v0.x, g);
            __builtin_nontemporal_store(v0.y, g + 1);
            t.x = v0.z; t.y = v0.w; t.z = v1.x; t.w = v1.y;
            __builtin_nontemporal_store(t, (vf4*)(g + 2));
            t.x = v1.z; t.y = v1.w; t.z = v2.x; t.w = v2.y;
            __builtin_nontemporal_store(t, (vf4*)(g + 6));
            t.x = v2.z; t.y = v2.w; t.z = v3.x; t.w = v3.y;
            __builtin_nontemporal_store(t, (vf4*)(g + 10));
            __builtin_nontemporal_store(v3.z, g + 14);
            __builtin_nontemporal_store(v3.w, g + 15);
            break;
          default:  // mis == 3
            __builtin_nontemporal_store(v0.x, g);
            __builtin_nontemporal_store(v0.y, g + 1);
            __builtin_nontemporal_store(v0.z, g + 2);
            t.x = v0.w; t.y = v1.x; t.z = v1.y; t.w = v1.z;
            __builtin_nontemporal_store(t, (vf4*)(g + 3));
            t.x = v1.w; t.y = v2.x; t.z = v2.y; t.w = v2.z;
            __builtin_nontemporal_store(t, (vf4*)(g + 7));
            t.x = v2.w; t.y = v3.x; t.z = v3.y; t.w = v3.z;
            __builtin_nontemporal_store(t, (vf4*)(g + 11));
            __builtin_nontemporal_store(v3.w, g + 15);
            break;
        }
      } else {
        #pragma unroll
        for (int p = 0; p < 4; ++p) {
          int c = p * 32 + sub * 4;
          #pragma unroll
          for (int e = 0; e < 4; ++e) {
            if (cb + c + e < NU) {
              float v = lrow[c + e];
              sum += v;
              __builtin_nontemporal_store(v, gout + c + e);
            }
          }
        }
      }
      sum += __shfl_xor(sum, 1, 64);
      sum += __shfl_xor(sum, 2, 64);
      sum += __shfl_xor(sum, 4, 64);
      if (sub == 0) atomicAdd(&row_sum[grow], sum);
    }
    __syncthreads();
  }
}

// ---------- sampled GEMM: gathers B rows straight from kbf via sampled[] ----
__global__ __launch_bounds__(256) void gemm_sampled(
    const unsigned short* __restrict__ A, const unsigned short* __restrict__ Kb,
    const float* __restrict__ adj, const int* __restrict__ sampled,
    const int* __restrict__ targets, float* __restrict__ loss_acc) {
  __shared__ alignas(16) unsigned short As[128 * 32];
  __shared__ alignas(16) unsigned short Bs[128 * 32];
  const int tid = threadIdx.x;
  const int wave = tid >> 6, lane = tid & 63;
  const int bid = blockIdx.x;
  const int sb = (bid & 7) * 128 + (bid >> 3);
  const int rb = (sb & 15) << 7;
  const int cb = (sb >> 4) << 7;
  const int wm = wave & 1, wn = wave >> 1;
  const int q = lane >> 4, l15 = lane & 15;
  const int srow = lane >> 2, scol = lane & 3;

  f32x4 acc[4][4] = {};

  const int seg0 = wave * 2;
  const unsigned short* ga0 = A + (size_t)(rb + seg0 * 16 + srow) * DK + scol * 8;
  const unsigned short* ga1 = ga0 + (size_t)16 * DK;
  int s0 = sampled[cb + seg0 * 16 + srow];
  int s1 = sampled[cb + (seg0 + 1) * 16 + srow];
  const unsigned short* gb0 = Kb + (size_t)s0 * DK + scol * 8;
  const unsigned short* gb1 = Kb + (size_t)s1 * DK + scol * 8;
  unsigned short* la0 = &As[(seg0) * 512];
  unsigned short* la1 = &As[(seg0 + 1) * 512];
  unsigned short* lb0 = &Bs[(seg0) * 512];
  unsigned short* lb1 = &Bs[(seg0 + 1) * 512];

  for (int kb = 0; kb < DK; kb += 32) {
    __builtin_amdgcn_global_load_lds((__attribute__((address_space(1))) void*)(ga0 + kb),
                                     (__attribute__((address_space(3))) void*)la0, 16, 0, 0);
    __builtin_amdgcn_global_load_lds((__attribute__((address_space(1))) void*)(ga1 + kb),
                                     (__attribute__((address_space(3))) void*)la1, 16, 0, 0);
    __builtin_amdgcn_global_load_lds((__attribute__((address_space(1))) void*)(gb0 + kb),
                                     (__attribute__((address_space(3))) void*)lb0, 16, 0, 0);
    __builtin_amdgcn_global_load_lds((__attribute__((address_space(1))) void*)(gb1 + kb),
                                     (__attribute__((address_space(3))) void*)lb1, 16, 0, 0);
    __syncthreads();
    bf16x8 af[4], bfr[4];
    #pragma unroll
    for (int mi = 0; mi < 4; ++mi)
      af[mi] = *(const bf16x8*)&As[(wm * 64 + mi * 16 + l15) * 32 + q * 8];
    #pragma unroll
    for (int ni = 0; ni < 4; ++ni)
      bfr[ni] = *(const bf16x8*)&Bs[(wn * 64 + ni * 16 + l15) * 32 + q * 8];
    #pragma unroll
    for (int mi = 0; mi < 4; ++mi)
      #pragma unroll
      for (int ni = 0; ni < 4; ++ni)
        acc[mi][ni] = __builtin_amdgcn_mfma_f32_16x16x32_bf16(af[mi], bfr[ni], acc[mi][ni], 0, 0, 0);
    __syncthreads();
  }

  #pragma unroll
  for (int mi = 0; mi < 4; ++mi) {
    int row0 = rb + wm * 64 + mi * 16 + q * 4;
    int t0 = targets[row0], t1 = targets[row0 + 1], t2 = targets[row0 + 2], t3 = targets[row0 + 3];
    float rs[4] = {0.f, 0.f, 0.f, 0.f};
    #pragma unroll
    for (int ni = 0; ni < 4; ++ni) {
      int col = cb + wn * 64 + ni * 16 + l15;
      float av = adj[col];
      int sid = sampled[col];
      f32x4 c = acc[mi][ni];
      rs[0] += (sid == t0) ? 0.f : __expf(c[0] + av);
      rs[1] += (sid == t1) ? 0.f : __expf(c[1] + av);
      rs[2] += (sid == t2) ? 0.f : __expf(c[2] + av);
      rs[3] += (sid == t3) ? 0.f : __expf(c[3] + av);
    }
    #pragma unroll
    for (int r = 0; r < 4; ++r) {
      float v = rs[r];
      v += __shfl_xor(v, 1, 64);
      v += __shfl_xor(v, 2, 64);
      v += __shfl_xor(v, 4, 64);
      v += __shfl_xor(v, 8, 64);
      if (l15 == 0) atomicAdd(&loss_acc[row0 + r], v);
    }
  }
}

// ---------- scale probs: one block per row, fused 1/row_sum, aligned body ----
__global__ __launch_bounds__(256) void scale_probs_rows(float* __restrict__ out,
                                                        const float* __restrict__ row_sum) {
  int row = blockIdx.x;
  size_t base = (size_t)row * NU;
  float inv = 1.0f / row_sum[row];
  float* p = out + base;
  int mis = (int)((4 - (base & 3)) & 3);
  int t = threadIdx.x;
  if (t < mis) p[t] *= inv;                 // head scalars (0..3)
  int nb = (NU - mis) >> 2;                 // full float4 count
  for (int j = t; j < nb; j += 256) {
    vf4* q = (vf4*)(p + mis + 4 * j);
    vf4 v = __builtin_nontemporal_load(q);
    v.x *= inv; v.y *= inv; v.z *= inv; v.w *= inv;
    __builtin_nontemporal_store(v, q);
  }
  int done = mis + 4 * nb;
  int rem = NU - done;                      // 0..3 tail scalars
  if (t < rem) p[done + t] *= inv;
}

// ---------- final loss reduce ----------
__global__ void finalize_loss(const float* __restrict__ loss_acc,
                              const float* __restrict__ true_logit,
                              float* __restrict__ loss_out) {
  __shared__ float red[256];
  float s = 0.f;
  for (int i = threadIdx.x; i < N_ROWS; i += 256)
    s += logf(loss_acc[i]) - true_logit[i];
  red[threadIdx.x] = s;
  __syncthreads();
  for (int off = 128; off > 0; off >>= 1) {
    if (threadIdx.x < off) red[threadIdx.x] += red[threadIdx.x + off];
    __syncthreads();
  }
  if (threadIdx.x == 0) loss_out[0] = red[0] / (float)N_ROWS;
}

extern "C" void kernel_launch(void* const* d_in, const int* in_sizes, int n_in,
                              void* d_out, int out_size, void* d_ws, size_t ws_size,
                              hipStream_t stream) {
  const float* x = (const float*)d_in[0];       // [2,1024,1024]
  const float* kern = (const float*)d_in[1];    // [50257,1024]
  const float* bias = (const float*)d_in[2];    // [50257]
  const int* targets = (const int*)d_in[3];     // [2048]
  const int* sampled = (const int*)d_in[4];     // [8192]
  float* out = (float*)d_out;                   // probs [2048*50257] then loss [1]

  char* ws = (char*)d_ws;
  size_t off = 0;
  unsigned short* kbf = (unsigned short*)(ws + off); off += (size_t)NU * DK * 2;     // 98.2 MiB
  unsigned short* xbf = (unsigned short*)(ws + off); off += (size_t)N_ROWS * DK * 2; // 4 MiB
  float* adj = (float*)(ws + off); off += (size_t)NS * 4;
  float* row_sum = (float*)(ws + off); off += (size_t)N_ROWS * 4;
  float* loss_acc = (float*)(ws + off); off += (size_t)N_ROWS * 4;
  float* true_l = (float*)(ws + off); off += (size_t)N_ROWS * 4;

  hipMemsetAsync(row_sum, 0, N_ROWS * 4, stream);
  hipMemsetAsync(loss_acc, 0, N_ROWS * 4, stream);

  {
    unsigned n = NU * DK;  // 51,463,168 (divisible by 8)
    cvt_f32_bf16<<<(n / 8 + 255) / 256, 256, 0, stream>>>(kern, kbf, n);
  }
  {
    unsigned n = N_ROWS * DK;
    cvt_f32_bf16<<<(n / 8 + 255) / 256, 256, 0, stream>>>(x, xbf, n);
  }
  compute_adj<<<(NS + 255) / 256, 256, 0, stream>>>(bias, sampled, adj);
  true_logits_k<<<N_ROWS / 4, 256, 0, stream>>>(x, kern, bias, targets, true_l, loss_acc);

  // 393 col panels x 16 row tiles = 6288 blocks (= 8 XCD chunks of 786)
  gemm_probs<<<dim3(6288), 256, 0, stream>>>(xbf, kbf, bias, out, row_sum);

  // 64 col panels x 16 row tiles = 1024 blocks (= 8 XCD chunks of 128)
  gemm_sampled<<<dim3(1024), 256, 0, stream>>>(xbf, kbf, adj, sampled, targets, loss_acc);

  scale_probs_rows<<<N_ROWS, 256, 0, stream>>>(out, row_sum);

  finalize_loss<<<1, 256, 0, stream>>>(loss_acc, true_l, out + (size_t)N_ROWS * NU);
}

// Round 5
// 1055.094 us; speedup vs baseline: 1.0842x; 1.0842x over previous
//
#include <hip/hip_runtime.h>
#include <hip/hip_bf16.h>
#include <stdint.h>

#define N_ROWS 2048
#define DK 1024
#define NU 50257
#define NS 8192
#define NPAN 393   // ceil(NU/128) column panels

typedef __bf16 bf16x8 __attribute__((ext_vector_type(8)));
typedef float f32x4 __attribute__((ext_vector_type(4)));
typedef float vf4 __attribute__((ext_vector_type(4)));   // clang-native for nt builtins
typedef unsigned vu2 __attribute__((ext_vector_type(2)));
typedef unsigned vu4 __attribute__((ext_vector_type(4)));

__device__ __forceinline__ unsigned short f2bf_rne(float f) {
  union { float f; unsigned u; } v; v.f = f;
  unsigned u = v.u;
  return (unsigned short)((u + 0x7FFFu + ((u >> 16) & 1u)) >> 16);
}
__device__ __forceinline__ unsigned pack2(float lo, float hi) {
  return (unsigned)f2bf_rne(lo) | ((unsigned)f2bf_rne(hi) << 16);
}

// ---------- fp32 -> bf16 bulk convert (8 elems/thread, 16B stores) ----------
__global__ void cvt_f32_bf16(const float* __restrict__ in,
                             unsigned short* __restrict__ out, unsigned n) {
  unsigned i = (blockIdx.x * 256u + threadIdx.x) * 8u;
  if (i >= n) return;
  const vf4* p = (const vf4*)(in + i);
  vf4 a = __builtin_nontemporal_load(p);
  vf4 b = __builtin_nontemporal_load(p + 1);
  vu4 o;
  o.x = pack2(a.x, a.y); o.y = pack2(a.z, a.w);
  o.z = pack2(b.x, b.y); o.w = pack2(b.z, b.w);
  *(vu4*)(out + i) = o;
}

// ---------- gather sampled rows to bf16 + per-col adjust term ----------
__global__ void gather_sampled(const float* __restrict__ kern,
                               const float* __restrict__ bias,
                               const int* __restrict__ sampled,
                               unsigned short* __restrict__ sw,
                               float* __restrict__ adj) {
  int j = blockIdx.x;
  int s = sampled[j];
  const float* src = kern + (size_t)s * DK;
  unsigned short* dst = sw + (size_t)j * DK;
  int c = threadIdx.x * 4;  // 256*4 == 1024
  vf4 v = __builtin_nontemporal_load((const vf4*)(src + c));
  vu2 o; o.x = pack2(v.x, v.y); o.y = pack2(v.z, v.w);
  *(vu2*)(dst + c) = o;
  if (threadIdx.x == 0) {
    float lq = logf(log1pf(1.0f / ((float)s + 1.0f))) - logf(logf((float)(NU + 1)));
    adj[j] = bias[s] - (logf((float)NS) + lq);
  }
}

// ---------- true logit per row (fp32 dot), adds exp(tl) into loss accum ----------
__global__ void true_logits_k(const float* __restrict__ x, const float* __restrict__ kern,
                              const float* __restrict__ bias, const int* __restrict__ targets,
                              float* __restrict__ true_logit, float* __restrict__ loss_acc) {
  int row = blockIdx.x * 4 + (threadIdx.x >> 6);
  int lane = threadIdx.x & 63;
  int t = targets[row];
  const float* xr = x + (size_t)row * DK;
  const float* wr = kern + (size_t)t * DK;
  float s = 0.f;
  #pragma unroll
  for (int it = 0; it < 4; ++it) {
    int c = lane * 4 + it * 256;
    float4 a = *(const float4*)(xr + c);
    float4 b = *(const float4*)(wr + c);
    s += a.x * b.x + a.y * b.y + a.z * b.z + a.w * b.w;
  }
  #pragma unroll
  for (int off = 32; off > 0; off >>= 1) s += __shfl_xor(s, off, 64);
  if (lane == 0) {
    float lq = logf(log1pf(1.0f / ((float)t + 1.0f))) - logf(logf((float)(NU + 1)));
    float tl = s + bias[t] - (logf((float)NS) + lq);
    true_logit[row] = tl;
    atomicAdd(&loss_acc[row], __expf(tl));
  }
}

// ---------- main GEMM: probs numerator + per-panel row sums ----------
// XCD-chunk swizzle (6288 = 8*786, bijective), row-inner -> B panel L2-reused
// 16x. Epilogue: LDS-staged 32x128 tile -> coalesced 128B-per-8-lane stores.
// NORMAL stores (not nt): L2 write-combines the misaligned row heads/tails
// (R0: 1.15x amp with normal vs R2: 1.36x with nt). Row sums go to a
// non-atomic [row][panel] partial array (atomics serialized ~6288 RMW/line).
__global__ __launch_bounds__(256) void gemm_probs(
    const unsigned short* __restrict__ A,   // x bf16 [2048,1024]
    const unsigned short* __restrict__ Bm,  // kernel bf16 [NU,1024]
    const float* __restrict__ bias,
    float* __restrict__ out, float* __restrict__ part) {
  __shared__ alignas(16) unsigned char smem[32 * 132 * 4];
  unsigned short* As = (unsigned short*)smem;
  unsigned short* Bs = (unsigned short*)(smem + 8192);
  float* ot = (float*)smem;

  const int tid = threadIdx.x;
  const int wave = tid >> 6, lane = tid & 63;
  const int bid = blockIdx.x;
  const int sb = (bid & 7) * 786 + (bid >> 3);   // XCD-chunk swizzle
  const int rb = (sb & 15) << 7;                 // row tile (inner)
  const int panel = sb >> 4;                     // col panel index
  const int cb = panel << 7;                     // col panel (outer)
  const int wm = wave & 1, wn = wave >> 1;
  const int q = lane >> 4, l15 = lane & 15;
  const int srow = lane >> 2, scol = lane & 3;

  f32x4 acc[4][4] = {};

  const int seg0 = wave * 2;
  const unsigned short* ga0 = A + (size_t)(rb + seg0 * 16 + srow) * DK + scol * 8;
  const unsigned short* ga1 = ga0 + (size_t)16 * DK;
  int bu0 = cb + seg0 * 16 + srow;       if (bu0 > NU - 1) bu0 = NU - 1;
  int bu1 = cb + (seg0 + 1) * 16 + srow; if (bu1 > NU - 1) bu1 = NU - 1;
  const unsigned short* gb0 = Bm + (size_t)bu0 * DK + scol * 8;
  const unsigned short* gb1 = Bm + (size_t)bu1 * DK + scol * 8;
  unsigned short* la0 = As + (seg0) * 512;
  unsigned short* la1 = As + (seg0 + 1) * 512;
  unsigned short* lb0 = Bs + (seg0) * 512;
  unsigned short* lb1 = Bs + (seg0 + 1) * 512;

  for (int kb = 0; kb < DK; kb += 32) {
    __builtin_amdgcn_global_load_lds((__attribute__((address_space(1))) void*)(ga0 + kb),
                                     (__attribute__((address_space(3))) void*)la0, 16, 0, 0);
    __builtin_amdgcn_global_load_lds((__attribute__((address_space(1))) void*)(ga1 + kb),
                                     (__attribute__((address_space(3))) void*)la1, 16, 0, 0);
    __builtin_amdgcn_global_load_lds((__attribute__((address_space(1))) void*)(gb0 + kb),
                                     (__attribute__((address_space(3))) void*)lb0, 16, 0, 0);
    __builtin_amdgcn_global_load_lds((__attribute__((address_space(1))) void*)(gb1 + kb),
                                     (__attribute__((address_space(3))) void*)lb1, 16, 0, 0);
    __syncthreads();
    bf16x8 af[4], bfr[4];
    #pragma unroll
    for (int mi = 0; mi < 4; ++mi)
      af[mi] = *(const bf16x8*)&As[(wm * 64 + mi * 16 + l15) * 32 + q * 8];
    #pragma unroll
    for (int ni = 0; ni < 4; ++ni)
      bfr[ni] = *(const bf16x8*)&Bs[(wn * 64 + ni * 16 + l15) * 32 + q * 8];
    #pragma unroll
    for (int mi = 0; mi < 4; ++mi)
      #pragma unroll
      for (int ni = 0; ni < 4; ++ni)
        acc[mi][ni] = __builtin_amdgcn_mfma_f32_16x16x32_bf16(af[mi], bfr[ni], acc[mi][ni], 0, 0, 0);
    __syncthreads();
  }

  // ---- epilogue: per mi-slice, stage 32x128 exp-tile in LDS, write coalesced
  const bool full_panel = (cb + 128 <= NU);
  #pragma unroll
  for (int mi = 0; mi < 4; ++mi) {
    // Phase A: fragment -> LDS with bias + exp
    #pragma unroll
    for (int ni = 0; ni < 4; ++ni) {
      int col = cb + wn * 64 + ni * 16 + l15;
      int bcol = col < NU ? col : NU - 1;   // clamp: avoid OOB bias read
      float bv = bias[bcol];
      f32x4 c = acc[mi][ni];
      #pragma unroll
      for (int r = 0; r < 4; ++r)
        ot[(wm * 16 + q * 4 + r) * 132 + wn * 64 + ni * 16 + l15] = __expf(c[r] + bv);
    }
    __syncthreads();
    // Phase B: coalesced write-back + row sums (non-atomic partials).
    {
      int lr = tid >> 3;          // 0..31 local row
      int sub = tid & 7;          // 0..7
      int grow = rb + (lr >> 4) * 64 + mi * 16 + (lr & 15);
      float* gout = out + (size_t)grow * NU + cb;
      const float* lrow = ot + lr * 132;
      float sum = 0.f;
      if (full_panel) {
        #pragma unroll
        for (int p = 0; p < 4; ++p) {
          int c = p * 32 + sub * 4;
          vf4 v = *(const vf4*)(lrow + c);
          sum += v.x + v.y + v.z + v.w;
          __builtin_memcpy(gout + c, &v, 16);   // normal store, L2 write-combine
        }
      } else {
        #pragma unroll
        for (int p = 0; p < 4; ++p) {
          int c = p * 32 + sub * 4;
          #pragma unroll
          for (int e = 0; e < 4; ++e) {
            if (cb + c + e < NU) {
              float v = lrow[c + e];
              sum += v;
              gout[c + e] = v;
            }
          }
        }
      }
      sum += __shfl_xor(sum, 1, 64);
      sum += __shfl_xor(sum, 2, 64);
      sum += __shfl_xor(sum, 4, 64);
      if (sub == 0) part[(size_t)grow * NPAN + panel] = sum;
    }
    __syncthreads();
  }
}

// ---------- sampled GEMM: fused exp-sum with accidental-hit masking ----------
__global__ __launch_bounds__(256) void gemm_sampled(
    const unsigned short* __restrict__ A, const unsigned short* __restrict__ SW,
    const float* __restrict__ adj, const int* __restrict__ sampled,
    const int* __restrict__ targets, float* __restrict__ loss_acc) {
  __shared__ alignas(16) unsigned short As[128 * 32];
  __shared__ alignas(16) unsigned short Bs[128 * 32];
  const int tid = threadIdx.x;
  const int wave = tid >> 6, lane = tid & 63;
  const int bid = blockIdx.x;
  const int sb = (bid & 7) * 128 + (bid >> 3);
  const int rb = (sb & 15) << 7;
  const int cb = (sb >> 4) << 7;
  const int wm = wave & 1, wn = wave >> 1;
  const int q = lane >> 4, l15 = lane & 15;
  const int srow = lane >> 2, scol = lane & 3;

  f32x4 acc[4][4] = {};

  const int seg0 = wave * 2;
  const unsigned short* ga0 = A + (size_t)(rb + seg0 * 16 + srow) * DK + scol * 8;
  const unsigned short* ga1 = ga0 + (size_t)16 * DK;
  const unsigned short* gb0 = SW + (size_t)(cb + seg0 * 16 + srow) * DK + scol * 8;
  const unsigned short* gb1 = gb0 + (size_t)16 * DK;
  unsigned short* la0 = &As[(seg0) * 512];
  unsigned short* la1 = &As[(seg0 + 1) * 512];
  unsigned short* lb0 = &Bs[(seg0) * 512];
  unsigned short* lb1 = &Bs[(seg0 + 1) * 512];

  for (int kb = 0; kb < DK; kb += 32) {
    __builtin_amdgcn_global_load_lds((__attribute__((address_space(1))) void*)(ga0 + kb),
                                     (__attribute__((address_space(3))) void*)la0, 16, 0, 0);
    __builtin_amdgcn_global_load_lds((__attribute__((address_space(1))) void*)(ga1 + kb),
                                     (__attribute__((address_space(3))) void*)la1, 16, 0, 0);
    __builtin_amdgcn_global_load_lds((__attribute__((address_space(1))) void*)(gb0 + kb),
                                     (__attribute__((address_space(3))) void*)lb0, 16, 0, 0);
    __builtin_amdgcn_global_load_lds((__attribute__((address_space(1))) void*)(gb1 + kb),
                                     (__attribute__((address_space(3))) void*)lb1, 16, 0, 0);
    __syncthreads();
    bf16x8 af[4], bfr[4];
    #pragma unroll
    for (int mi = 0; mi < 4; ++mi)
      af[mi] = *(const bf16x8*)&As[(wm * 64 + mi * 16 + l15) * 32 + q * 8];
    #pragma unroll
    for (int ni = 0; ni < 4; ++ni)
      bfr[ni] = *(const bf16x8*)&Bs[(wn * 64 + ni * 16 + l15) * 32 + q * 8];
    #pragma unroll
    for (int mi = 0; mi < 4; ++mi)
      #pragma unroll
      for (int ni = 0; ni < 4; ++ni)
        acc[mi][ni] = __builtin_amdgcn_mfma_f32_16x16x32_bf16(af[mi], bfr[ni], acc[mi][ni], 0, 0, 0);
    __syncthreads();
  }

  #pragma unroll
  for (int mi = 0; mi < 4; ++mi) {
    int row0 = rb + wm * 64 + mi * 16 + q * 4;
    int t0 = targets[row0], t1 = targets[row0 + 1], t2 = targets[row0 + 2], t3 = targets[row0 + 3];
    float rs[4] = {0.f, 0.f, 0.f, 0.f};
    #pragma unroll
    for (int ni = 0; ni < 4; ++ni) {
      int col = cb + wn * 64 + ni * 16 + l15;
      float av = adj[col];
      int sid = sampled[col];
      f32x4 c = acc[mi][ni];
      rs[0] += (sid == t0) ? 0.f : __expf(c[0] + av);
      rs[1] += (sid == t1) ? 0.f : __expf(c[1] + av);
      rs[2] += (sid == t2) ? 0.f : __expf(c[2] + av);
      rs[3] += (sid == t3) ? 0.f : __expf(c[3] + av);
    }
    #pragma unroll
    for (int r = 0; r < 4; ++r) {
      float v = rs[r];
      v += __shfl_xor(v, 1, 64);
      v += __shfl_xor(v, 2, 64);
      v += __shfl_xor(v, 4, 64);
      v += __shfl_xor(v, 8, 64);
      if (l15 == 0) atomicAdd(&loss_acc[row0 + r], v);
    }
  }
}

// ---------- reduce per-panel partials -> 1/row_sum ----------
__global__ void reduce_inv(const float* __restrict__ part, float* __restrict__ inv) {
  int row = blockIdx.x;
  const float* pr = part + (size_t)row * NPAN;
  float s = 0.f;
  for (int i = threadIdx.x; i < NPAN; i += 64) s += pr[i];
  #pragma unroll
  for (int off = 32; off > 0; off >>= 1) s += __shfl_xor(s, off, 64);
  if (threadIdx.x == 0) inv[row] = 1.0f / s;
}

// ---------- scale probs: 2D grid, row-uniform inv, 64B-aligned body ----------
__global__ __launch_bounds__(256) void scale_probs2(float* __restrict__ out,
                                                    const float* __restrict__ inv_rs) {
  int row = blockIdx.y;
  size_t base = (size_t)row * NU;
  float inv = inv_rs[row];
  float* p = out + base;
  int mis = (int)((4 - (base & 3)) & 3);    // scalars to reach 16B alignment
  int t = threadIdx.x;
  if (blockIdx.x == 0 && t < mis) p[t] *= inv;
  int start = mis + blockIdx.x * 4096;      // aligned float index
  #pragma unroll
  for (int u = 0; u < 4; ++u) {
    int j = start + t * 4 + u * 1024;
    if (j + 4 <= NU) {
      vf4* q = (vf4*)(p + j);
      vf4 v = __builtin_nontemporal_load(q);
      v.x *= inv; v.y *= inv; v.z *= inv; v.w *= inv;
      __builtin_nontemporal_store(v, q);
    } else if (j < NU) {
      for (int e = 0; e < NU - j; ++e) p[j + e] *= inv;
    }
  }
}

// ---------- final loss reduce ----------
__global__ void finalize_loss(const float* __restrict__ loss_acc,
                              const float* __restrict__ true_logit,
                              float* __restrict__ loss_out) {
  __shared__ float red[256];
  float s = 0.f;
  for (int i = threadIdx.x; i < N_ROWS; i += 256)
    s += logf(loss_acc[i]) - true_logit[i];
  red[threadIdx.x] = s;
  __syncthreads();
  for (int off = 128; off > 0; off >>= 1) {
    if (threadIdx.x < off) red[threadIdx.x] += red[threadIdx.x + off];
    __syncthreads();
  }
  if (threadIdx.x == 0) loss_out[0] = red[0] / (float)N_ROWS;
}

extern "C" void kernel_launch(void* const* d_in, const int* in_sizes, int n_in,
                              void* d_out, int out_size, void* d_ws, size_t ws_size,
                              hipStream_t stream) {
  const float* x = (const float*)d_in[0];       // [2,1024,1024]
  const float* kern = (const float*)d_in[1];    // [50257,1024]
  const float* bias = (const float*)d_in[2];    // [50257]
  const int* targets = (const int*)d_in[3];     // [2048]
  const int* sampled = (const int*)d_in[4];     // [8192]
  float* out = (float*)d_out;                   // probs [2048*50257] then loss [1]

  char* ws = (char*)d_ws;
  size_t off = 0;
  unsigned short* kbf = (unsigned short*)(ws + off); off += (size_t)NU * DK * 2;     // 98.2 MiB
  unsigned short* xbf = (unsigned short*)(ws + off); off += (size_t)N_ROWS * DK * 2; // 4 MiB
  unsigned short* swbf = (unsigned short*)(ws + off); off += (size_t)NS * DK * 2;    // 16 MiB
  float* adj = (float*)(ws + off); off += (size_t)NS * 4;
  float* part = (float*)(ws + off); off += (size_t)N_ROWS * NPAN * 4;                // 3.2 MiB
  float* inv_rs = (float*)(ws + off); off += (size_t)N_ROWS * 4;
  float* loss_acc = (float*)(ws + off); off += (size_t)N_ROWS * 4;
  float* true_l = (float*)(ws + off); off += (size_t)N_ROWS * 4;

  hipMemsetAsync(loss_acc, 0, N_ROWS * 4, stream);

  {
    unsigned n = NU * DK;  // 51,463,168 (divisible by 8)
    cvt_f32_bf16<<<(n / 8 + 255) / 256, 256, 0, stream>>>(kern, kbf, n);
  }
  {
    unsigned n = N_ROWS * DK;
    cvt_f32_bf16<<<(n / 8 + 255) / 256, 256, 0, stream>>>(x, xbf, n);
  }
  gather_sampled<<<NS, 256, 0, stream>>>(kern, bias, sampled, swbf, adj);
  true_logits_k<<<N_ROWS / 4, 256, 0, stream>>>(x, kern, bias, targets, true_l, loss_acc);

  // 393 col panels x 16 row tiles = 6288 blocks (= 8 XCD chunks of 786)
  gemm_probs<<<dim3(6288), 256, 0, stream>>>(xbf, kbf, bias, out, part);

  // 64 col panels x 16 row tiles = 1024 blocks (= 8 XCD chunks of 128)
  gemm_sampled<<<dim3(1024), 256, 0, stream>>>(xbf, swbf, adj, sampled, targets, loss_acc);

  reduce_inv<<<N_ROWS, 64, 0, stream>>>(part, inv_rs);

  // 13 x-chunks of 4096 aligned floats cover NU=50257 per row
  scale_probs2<<<dim3(13, N_ROWS), 256, 0, stream>>>(out, inv_rs);

  finalize_loss<<<1, 256, 0, stream>>>(loss_acc, true_l, out + (size_t)N_ROWS * NU);
}